// Round 1
// baseline (432.697 us; speedup 1.0000x reference)
//
#include <hip/hip_runtime.h>
#include <hip/hip_bf16.h>

// Problem: out[B,S,D_OUT] = x[B,S,D_IN] @ sign(W)[D_OUT,D_IN]^T + bias
// As GEMM: M = B*S = 8192, N = D_OUT = 4096, K = D_IN = 4096, all fp32 in/out.
// Strategy: cast x -> bf16, sign(W) -> bf16 (exact +-1), bf16 MFMA GEMM
// (m97-verified 128x128 tile structure), fp32 epilogue with bias.

#define M_DIM 8192
#define N_DIM 4096
#define K_DIM 4096
#define BM 128
#define BN 128
#define BK 32

typedef __attribute__((ext_vector_type(8))) short bf16x8;
typedef __attribute__((ext_vector_type(4))) float f32x4;
typedef __attribute__((ext_vector_type(8))) unsigned short u16x8;

// ---------- conversion helpers ----------

__device__ __forceinline__ unsigned short f2bf_rne(float f) {
    unsigned u = __float_as_uint(f);
    unsigned r = (u + 0x7FFFu + ((u >> 16) & 1u)) >> 16;
    return (unsigned short)r;
}

__device__ __forceinline__ unsigned short sign_bf(float f) {
    // sign(): +1 / -1 / 0 (handles -0.0 -> 0). bf16 +-1.0 is exact.
    if (f == 0.0f) return 0;
    return (unsigned short)(0x3F80u | ((__float_as_uint(f) >> 16) & 0x8000u));
}

// x: fp32 -> bf16, 8 elems/thread, vectorized
__global__ __launch_bounds__(256) void cvt_x_kernel(
    const float* __restrict__ in, unsigned short* __restrict__ out, long nvec8) {
    long i = (long)blockIdx.x * blockDim.x + threadIdx.x;
    if (i >= nvec8) return;
    const float4* p = reinterpret_cast<const float4*>(in) + i * 2;
    float4 v0 = p[0];
    float4 v1 = p[1];
    u16x8 r;
    r[0] = f2bf_rne(v0.x); r[1] = f2bf_rne(v0.y);
    r[2] = f2bf_rne(v0.z); r[3] = f2bf_rne(v0.w);
    r[4] = f2bf_rne(v1.x); r[5] = f2bf_rne(v1.y);
    r[6] = f2bf_rne(v1.z); r[7] = f2bf_rne(v1.w);
    reinterpret_cast<u16x8*>(out)[i] = r;
}

// w: fp32 -> sign in bf16, 8 elems/thread
__global__ __launch_bounds__(256) void cvt_w_kernel(
    const float* __restrict__ in, unsigned short* __restrict__ out, long nvec8) {
    long i = (long)blockIdx.x * blockDim.x + threadIdx.x;
    if (i >= nvec8) return;
    const float4* p = reinterpret_cast<const float4*>(in) + i * 2;
    float4 v0 = p[0];
    float4 v1 = p[1];
    u16x8 r;
    r[0] = sign_bf(v0.x); r[1] = sign_bf(v0.y);
    r[2] = sign_bf(v0.z); r[3] = sign_bf(v0.w);
    r[4] = sign_bf(v1.x); r[5] = sign_bf(v1.y);
    r[6] = sign_bf(v1.z); r[7] = sign_bf(v1.w);
    reinterpret_cast<u16x8*>(out)[i] = r;
}

// ---------- async global->LDS (16B per lane; dest = wave-uniform base + lane*16) ----------

__device__ __forceinline__ void gload_lds16(const unsigned short* g, unsigned short* l) {
    __builtin_amdgcn_global_load_lds(
        (const __attribute__((address_space(1))) unsigned int*)g,
        (__attribute__((address_space(3))) unsigned int*)l,
        16, 0, 0);
}

// ---------- main GEMM: C[M][N] = A[M][K] * Bt[N][K]^T + bias ----------
// m97 structure: 128x128 tile, BK=32, 256 threads (4 waves, 2x2),
// each wave computes 64x64 = 4x4 fragments of 16x16, mfma_f32_16x16x32_bf16.

__global__ __launch_bounds__(256) void gemm_bt_bf16(
    const unsigned short* __restrict__ A,   // [M][K] bf16 bits
    const unsigned short* __restrict__ Bt,  // [N][K] bf16 bits (sign weights)
    const float* __restrict__ bias,         // [N]
    float* __restrict__ C)                  // [M][N] fp32
{
    __shared__ __align__(16) unsigned short As[BM * BK];  // 8 KiB
    __shared__ __align__(16) unsigned short Bs[BN * BK];  // 8 KiB

    const int tid  = threadIdx.x;
    const int lane = tid & 63;
    const int wave = tid >> 6;   // 0..3
    const int wr   = wave >> 1;  // wave row (0..1) -> 64-row slab
    const int wc   = wave & 1;   // wave col (0..1) -> 64-col slab

    // XCD-aware bijective swizzle (grid = 64*32 = 2048, divisible by 8)
    const int nwg = gridDim.x;
    const int cpx = nwg >> 3;
    int bid = blockIdx.x;
    bid = (bid & 7) * cpx + (bid >> 3);

    const int ntile = N_DIM / BN;  // 32
    const int tm = bid / ntile;
    const int tn = bid % ntile;
    const long brow = (long)tm * BM;
    const long bcol = (long)tn * BN;

    // Staging: per issue a wave covers 16 rows x 32 cols (1024 B).
    // lane l -> row l/4, 16B chunk (l%4) within the row.
    const int srow = lane >> 2;
    const int scol = (lane & 3) * 8;

    const unsigned short* a_src0 = A  + (brow + wave * 16 + srow) * (long)K_DIM + scol;
    const unsigned short* a_src1 = a_src0 + 64 * (long)K_DIM;
    const unsigned short* b_src0 = Bt + (bcol + wave * 16 + srow) * (long)K_DIM + scol;
    const unsigned short* b_src1 = b_src0 + 64 * (long)K_DIM;

    unsigned short* a_dst0 = As + (wave * 16) * BK;        // wave-uniform LDS bases
    unsigned short* a_dst1 = As + (64 + wave * 16) * BK;
    unsigned short* b_dst0 = Bs + (wave * 16) * BK;
    unsigned short* b_dst1 = Bs + (64 + wave * 16) * BK;

    // Fragment reads: lane l holds row (l&15), k-chunk (l>>4)*8 .. +8 (K-contiguous).
    const int fr = lane & 15;
    const int fq = lane >> 4;
    const unsigned short* a_rd = As + (wr * 64 + fr) * BK + fq * 8;
    const unsigned short* b_rd = Bs + (wc * 64 + fr) * BK + fq * 8;

    f32x4 acc[4][4];
#pragma unroll
    for (int i = 0; i < 4; ++i)
#pragma unroll
        for (int j = 0; j < 4; ++j) acc[i][j] = (f32x4){0.f, 0.f, 0.f, 0.f};

    for (int kt = 0; kt < K_DIM; kt += BK) {
        __syncthreads();  // previous compute done before overwrite
        gload_lds16(a_src0 + kt, a_dst0);
        gload_lds16(a_src1 + kt, a_dst1);
        gload_lds16(b_src0 + kt, b_dst0);
        gload_lds16(b_src1 + kt, b_dst1);
        __syncthreads();  // compiler drains vmcnt(0) before barrier

        bf16x8 afr[4], bfr[4];
#pragma unroll
        for (int m = 0; m < 4; ++m)
            afr[m] = *reinterpret_cast<const bf16x8*>(a_rd + m * 16 * BK);
#pragma unroll
        for (int n = 0; n < 4; ++n)
            bfr[n] = *reinterpret_cast<const bf16x8*>(b_rd + n * 16 * BK);

#pragma unroll
        for (int m = 0; m < 4; ++m)
#pragma unroll
            for (int n = 0; n < 4; ++n)
                acc[m][n] = __builtin_amdgcn_mfma_f32_16x16x32_bf16(
                    afr[m], bfr[n], acc[m][n], 0, 0, 0);
    }

    // Epilogue: C/D layout (16x16): col = lane&15, row = (lane>>4)*4 + j
#pragma unroll
    for (int n = 0; n < 4; ++n) {
        const long cg = bcol + wc * 64 + n * 16 + fr;
        const float bv = bias[cg];
#pragma unroll
        for (int m = 0; m < 4; ++m) {
            const long rbase = brow + wr * 64 + m * 16 + fq * 4;
#pragma unroll
            for (int j = 0; j < 4; ++j) {
                C[(rbase + j) * (long)N_DIM + cg] = acc[m][n][j] + bv;
            }
        }
    }
}

// ---------- naive fallback (only if ws_size is unexpectedly small) ----------

__global__ __launch_bounds__(256) void naive_kernel(
    const float* __restrict__ x, const float* __restrict__ w,
    const float* __restrict__ bias, float* __restrict__ out, long total) {
    long gid = (long)blockIdx.x * blockDim.x + threadIdx.x;
    if (gid >= total) return;
    long m = gid / N_DIM, n = gid % N_DIM;
    const float* xr = x + m * (long)K_DIM;
    const float* wr = w + n * (long)K_DIM;
    float s = 0.f;
    for (int k = 0; k < K_DIM; ++k) {
        float wv = wr[k];
        float sg = (wv > 0.f) ? 1.f : ((wv < 0.f) ? -1.f : 0.f);
        s += xr[k] * sg;
    }
    out[gid] = s + bias[n];
}

// ---------- launch ----------

extern "C" void kernel_launch(void* const* d_in, const int* in_sizes, int n_in,
                              void* d_out, int out_size, void* d_ws, size_t ws_size,
                              hipStream_t stream) {
    const float* x    = (const float*)d_in[0];  // [8192, 4096]
    const float* w    = (const float*)d_in[1];  // [4096, 4096]
    const float* bias = (const float*)d_in[2];  // [4096]
    float* out = (float*)d_out;                 // [8192, 4096]

    const size_t nA = (size_t)M_DIM * K_DIM;  // x elements
    const size_t nB = (size_t)N_DIM * K_DIM;  // w elements
    const size_t need_bytes = (nA + nB) * sizeof(unsigned short);  // 96 MiB

    if (ws_size >= need_bytes) {
        unsigned short* xb = (unsigned short*)d_ws;
        unsigned short* wb = xb + nA;

        {
            long nvec8 = (long)(nA / 8);
            int blocks = (int)((nvec8 + 255) / 256);
            cvt_x_kernel<<<blocks, 256, 0, stream>>>(x, xb, nvec8);
        }
        {
            long nvec8 = (long)(nB / 8);
            int blocks = (int)((nvec8 + 255) / 256);
            cvt_w_kernel<<<blocks, 256, 0, stream>>>(w, wb, nvec8);
        }
        dim3 grid((M_DIM / BM) * (N_DIM / BN));  // 64 * 32 = 2048
        gemm_bt_bf16<<<grid, 256, 0, stream>>>(xb, wb, bias, out);
    } else {
        long total = (long)M_DIM * N_DIM;
        int blocks = (int)((total + 255) / 256);
        naive_kernel<<<blocks, 256, 0, stream>>>(x, w, bias, out, total);
    }
}

// Round 2
// 343.053 us; speedup vs baseline: 1.2613x; 1.2613x over previous
//
#include <hip/hip_runtime.h>
#include <hip/hip_bf16.h>

// out[B,S,D_OUT] = x @ sign(W)^T + bias  ==  GEMM M=8192, N=4096, K=4096.
// Round 2: 256x256 8-phase pipelined bf16 MFMA GEMM (m201 template port):
// T1 XCD swizzle + T2 LDS XOR-swizzle + T3/T4 phased counted-vmcnt + T5 setprio.

#define M_DIM 8192
#define N_DIM 4096
#define K_DIM 4096
#define BM 256
#define BN 256
#define BK 64
#define NT (K_DIM / BK)  // 64

typedef __attribute__((ext_vector_type(8))) short bf16x8;
typedef __attribute__((ext_vector_type(4))) float f32x4;
typedef __attribute__((ext_vector_type(8))) unsigned short u16x8;

// ---------- conversion helpers ----------

__device__ __forceinline__ unsigned short f2bf_rne(float f) {
    unsigned u = __float_as_uint(f);
    unsigned r = (u + 0x7FFFu + ((u >> 16) & 1u)) >> 16;
    return (unsigned short)r;
}

__device__ __forceinline__ unsigned short sign_bf(float f) {
    if (f == 0.0f) return 0;
    return (unsigned short)(0x3F80u | ((__float_as_uint(f) >> 16) & 0x8000u));
}

__global__ __launch_bounds__(256) void cvt_x_kernel(
    const float* __restrict__ in, unsigned short* __restrict__ out, long nvec8) {
    long i = (long)blockIdx.x * blockDim.x + threadIdx.x;
    if (i >= nvec8) return;
    const float4* p = reinterpret_cast<const float4*>(in) + i * 2;
    float4 v0 = p[0];
    float4 v1 = p[1];
    u16x8 r;
    r[0] = f2bf_rne(v0.x); r[1] = f2bf_rne(v0.y);
    r[2] = f2bf_rne(v0.z); r[3] = f2bf_rne(v0.w);
    r[4] = f2bf_rne(v1.x); r[5] = f2bf_rne(v1.y);
    r[6] = f2bf_rne(v1.z); r[7] = f2bf_rne(v1.w);
    reinterpret_cast<u16x8*>(out)[i] = r;
}

__global__ __launch_bounds__(256) void cvt_w_kernel(
    const float* __restrict__ in, unsigned short* __restrict__ out, long nvec8) {
    long i = (long)blockIdx.x * blockDim.x + threadIdx.x;
    if (i >= nvec8) return;
    const float4* p = reinterpret_cast<const float4*>(in) + i * 2;
    float4 v0 = p[0];
    float4 v1 = p[1];
    u16x8 r;
    r[0] = sign_bf(v0.x); r[1] = sign_bf(v0.y);
    r[2] = sign_bf(v0.z); r[3] = sign_bf(v0.w);
    r[4] = sign_bf(v1.x); r[5] = sign_bf(v1.y);
    r[6] = sign_bf(v1.z); r[7] = sign_bf(v1.w);
    reinterpret_cast<u16x8*>(out)[i] = r;
}

// ---------- async global->LDS (16B/lane; LDS dest = wave-uniform base + lane*16) ----------

__device__ __forceinline__ void GL16(const unsigned short* g, unsigned short* l) {
    __builtin_amdgcn_global_load_lds(
        (const __attribute__((address_space(1))) unsigned int*)g,
        (__attribute__((address_space(3))) unsigned int*)l, 16, 0, 0);
}

// ---------- 256x256 8-phase GEMM ----------
// 512 threads = 8 waves (2 M x 4 N). Per wave: 128x64 output = 8x4 frags 16x16.
// LDS: A,B tiles [256][BK=64] bf16, double-buffered = 128 KiB.
// Swizzle: in-row 16B-chunk g stored at g ^ (row&7) (inverse-swizzled global src,
// linear gload_lds dest, swizzled ds_read) -> bank-uniform b128 reads.
// Phase schedule per K-tile t (cur = t&1), all staging airtight (region dead
// >=1 phase before its stage is issued):
//   ph1: read A m0-3(kk0,1), B n0-1 | stage tile t+1 A-m47 -> buf cur^1 | mfma m0-3 x n0-1
//   ph2: read B n2-3            | stage tile t+2 B-n01 -> buf cur      | mfma m0-3 x n2-3
//   ph3: read A m4-7            | stage tile t+2 B-n23 -> buf cur      | mfma m4-7 x n0-1
//   ph4: (no reads)             | stage tile t+2 A-m03 -> buf cur      | mfma m4-7 x n2-3
//        then s_waitcnt vmcnt(6) (tail: vmcnt(0)), end barrier.
// vmcnt(6) leaves only this half's ph2-4 issues in flight => next tile landed.

__global__ __launch_bounds__(512, 2) void gemm256(
    const unsigned short* __restrict__ A,   // [M][K] bf16 bits
    const unsigned short* __restrict__ Bt,  // [N][K] bf16 bits (sign weights)
    const float* __restrict__ bias,         // [N]
    float* __restrict__ C)                  // [M][N] fp32
{
    __shared__ __align__(16) unsigned short As[2][BM * BK];  // 2 x 32 KiB
    __shared__ __align__(16) unsigned short Bs[2][BN * BK];  // 2 x 32 KiB

    const int tid  = threadIdx.x;
    const int lane = tid & 63;
    const int w    = tid >> 6;   // 0..7
    const int wr   = w >> 2;     // 0..1 -> 128-row slab
    const int wc   = w & 3;      // 0..3 -> 64-col slab
    const int w8   = w * 8;

    // T1: XCD-aware bijective swizzle (grid = 32*16 = 512, divisible by 8)
    int bid = blockIdx.x;
    const int cpx = gridDim.x >> 3;
    bid = (bid & 7) * cpx + (bid >> 3);
    const int ntile = N_DIM / BN;  // 16
    const long brow = (long)(bid / ntile) * BM;
    const long bcol = (long)(bid % ntile) * BN;

    // ----- staging addressing -----
    // Each GL16 call: one wave covers 8 rows x 64 cols (1 KiB). lane -> row
    // lane>>3 within the 8-row group, phys 16B-chunk lane&7. Global source is
    // inverse-swizzled: chunk (lane&7) ^ (lane>>3).
    const int wrow8 = lane >> 3;
    const int colsw = (((lane & 7) ^ wrow8)) * 8;  // elements

    const unsigned short* gA = A  + brow * K_DIM + colsw;
    const unsigned short* gB = Bt + bcol * K_DIM + colsw;
    const int aw = w8 + wrow8;
    const int bw = (w >> 2) * 64 + (w & 3) * 8 + wrow8;

    // A units (64 rows each): U0 rows 0-63, U1 128-191 (m0-3 of each half);
    //                         U2 64-127, U3 192-255 (m4-7).
    const unsigned short* aU0 = gA + (long)(0   + aw) * K_DIM;
    const unsigned short* aU1 = gA + (long)(128 + aw) * K_DIM;
    const unsigned short* aU2 = gA + (long)(64  + aw) * K_DIM;
    const unsigned short* aU3 = gA + (long)(192 + aw) * K_DIM;
    // B units (8x8-row chunks): B0a rows {0-31,64-95}, B0b +128 (n0-1 of slabs);
    //                           B1a {32-63,96-127}, B1b +128 (n2-3).
    const unsigned short* bU0a = gB + (long)(0   + bw) * K_DIM;
    const unsigned short* bU0b = gB + (long)(128 + bw) * K_DIM;
    const unsigned short* bU1a = gB + (long)(32  + bw) * K_DIM;
    const unsigned short* bU1b = gB + (long)(160 + bw) * K_DIM;

    const int bb = ((w >> 2) * 64 + (w & 3) * 8) * 64;  // B LDS wave base (ushort)

    // ----- fragment read addressing (swizzled) -----
    const int fr = lane & 15;
    const int fq = lane >> 4;                       // 0..3
    const int rqu = (fq * 8) ^ ((lane & 7) << 3);   // swizzled in-row ushort off (kk=0)
    const int aoff0 = (wr * 128 + fr) * 64 + rqu;
    const int aoff1 = aoff0 ^ 32;                   // kk=1
    const int boff0 = (wc * 64 + fr) * 64 + rqu;
    const int boff1 = boff0 ^ 32;

    f32x4 acc[8][4];
#pragma unroll
    for (int m = 0; m < 8; ++m)
#pragma unroll
        for (int n = 0; n < 4; ++n) acc[m][n] = (f32x4){0.f, 0.f, 0.f, 0.f};

    bf16x8 a[4][2], b[4][2];

    // ----- prologue: stage tile0 fully + tile1 minus its A-m47 (U2,U3) -----
    GL16(aU0,  &As[0][(0   + w8) * 64]);
    GL16(aU1,  &As[0][(128 + w8) * 64]);
    GL16(aU2,  &As[0][(64  + w8) * 64]);
    GL16(aU3,  &As[0][(192 + w8) * 64]);
    GL16(bU0a, &Bs[0][bb]);
    GL16(bU0b, &Bs[0][bb + 128 * 64]);
    GL16(bU1a, &Bs[0][bb + 32 * 64]);
    GL16(bU1b, &Bs[0][bb + 160 * 64]);
    GL16(aU0  + BK, &As[1][(0   + w8) * 64]);
    GL16(aU1  + BK, &As[1][(128 + w8) * 64]);
    GL16(bU0a + BK, &Bs[1][bb]);
    GL16(bU0b + BK, &Bs[1][bb + 128 * 64]);
    GL16(bU1a + BK, &Bs[1][bb + 32 * 64]);
    GL16(bU1b + BK, &Bs[1][bb + 160 * 64]);
    asm volatile("s_waitcnt vmcnt(6)" ::: "memory");  // tile0 landed; tile1's 6 in flight
    __builtin_amdgcn_s_barrier();

    for (int t = 0; t < NT; ++t) {
        const int cur = t & 1;
        const long kt1 = (long)(t + 1) * BK;
        const long kt2 = (long)(t + 2) * BK;
        const bool st1 = (t + 1 < NT);
        const bool st2 = (t + 2 < NT);

        // ---------------- phase 1 ----------------
#pragma unroll
        for (int i = 0; i < 4; ++i) {
            a[i][0] = *reinterpret_cast<const bf16x8*>(&As[cur][aoff0 + i * 1024]);
            a[i][1] = *reinterpret_cast<const bf16x8*>(&As[cur][aoff1 + i * 1024]);
        }
#pragma unroll
        for (int n = 0; n < 2; ++n) {
            b[n][0] = *reinterpret_cast<const bf16x8*>(&Bs[cur][boff0 + n * 1024]);
            b[n][1] = *reinterpret_cast<const bf16x8*>(&Bs[cur][boff1 + n * 1024]);
        }
        if (st1) {  // tile t+1's A-m47 -> idle buffer (dead since last half's ph3)
            GL16(aU2 + kt1, &As[cur ^ 1][(64  + w8) * 64]);
            GL16(aU3 + kt1, &As[cur ^ 1][(192 + w8) * 64]);
        }
        __builtin_amdgcn_s_barrier();
        asm volatile("s_waitcnt lgkmcnt(0)" ::: "memory");
        __builtin_amdgcn_sched_barrier(0);
        __builtin_amdgcn_s_setprio(1);
#pragma unroll
        for (int m = 0; m < 4; ++m)
#pragma unroll
            for (int n = 0; n < 2; ++n)
#pragma unroll
                for (int kk = 0; kk < 2; ++kk)
                    acc[m][n] = __builtin_amdgcn_mfma_f32_16x16x32_bf16(
                        a[m][kk], b[n][kk], acc[m][n], 0, 0, 0);
        __builtin_amdgcn_s_setprio(0);
        __builtin_amdgcn_s_barrier();

        // ---------------- phase 2 ----------------
#pragma unroll
        for (int n = 2; n < 4; ++n) {
            b[n][0] = *reinterpret_cast<const bf16x8*>(&Bs[cur][boff0 + n * 1024]);
            b[n][1] = *reinterpret_cast<const bf16x8*>(&Bs[cur][boff1 + n * 1024]);
        }
        if (st2) {  // tile t+2's B-n01 (region dead after ph1)
            GL16(bU0a + kt2, &Bs[cur][bb]);
            GL16(bU0b + kt2, &Bs[cur][bb + 128 * 64]);
        }
        __builtin_amdgcn_s_barrier();
        asm volatile("s_waitcnt lgkmcnt(0)" ::: "memory");
        __builtin_amdgcn_sched_barrier(0);
        __builtin_amdgcn_s_setprio(1);
#pragma unroll
        for (int m = 0; m < 4; ++m)
#pragma unroll
            for (int n = 2; n < 4; ++n)
#pragma unroll
                for (int kk = 0; kk < 2; ++kk)
                    acc[m][n] = __builtin_amdgcn_mfma_f32_16x16x32_bf16(
                        a[m][kk], b[n][kk], acc[m][n], 0, 0, 0);
        __builtin_amdgcn_s_setprio(0);
        __builtin_amdgcn_s_barrier();

        // ---------------- phase 3 ----------------
#pragma unroll
        for (int i = 0; i < 4; ++i) {
            a[i][0] = *reinterpret_cast<const bf16x8*>(&As[cur][aoff0 + (i + 4) * 1024]);
            a[i][1] = *reinterpret_cast<const bf16x8*>(&As[cur][aoff1 + (i + 4) * 1024]);
        }
        if (st2) {  // tile t+2's B-n23 (dead after ph2)
            GL16(bU1a + kt2, &Bs[cur][bb + 32 * 64]);
            GL16(bU1b + kt2, &Bs[cur][bb + 160 * 64]);
        }
        __builtin_amdgcn_s_barrier();
        asm volatile("s_waitcnt lgkmcnt(0)" ::: "memory");
        __builtin_amdgcn_sched_barrier(0);
        __builtin_amdgcn_s_setprio(1);
#pragma unroll
        for (int i = 0; i < 4; ++i)
#pragma unroll
            for (int n = 0; n < 2; ++n)
#pragma unroll
                for (int kk = 0; kk < 2; ++kk)
                    acc[i + 4][n] = __builtin_amdgcn_mfma_f32_16x16x32_bf16(
                        a[i][kk], b[n][kk], acc[i + 4][n], 0, 0, 0);
        __builtin_amdgcn_s_setprio(0);
        __builtin_amdgcn_s_barrier();

        // ---------------- phase 4 ----------------
        if (st2) {  // tile t+2's A-m03 (dead after ph1)
            GL16(aU0 + kt2, &As[cur][(0   + w8) * 64]);
            GL16(aU1 + kt2, &As[cur][(128 + w8) * 64]);
        }
        __builtin_amdgcn_s_barrier();
        __builtin_amdgcn_s_setprio(1);
#pragma unroll
        for (int i = 0; i < 4; ++i)
#pragma unroll
            for (int n = 2; n < 4; ++n)
#pragma unroll
                for (int kk = 0; kk < 2; ++kk)
                    acc[i + 4][n] = __builtin_amdgcn_mfma_f32_16x16x32_bf16(
                        a[i][kk], b[n][kk], acc[i + 4][n], 0, 0, 0);
        __builtin_amdgcn_s_setprio(0);
        // Counted drain: everything except this half's ph2-4 issues has landed
        // => next K-tile fully present before any wave crosses into ph1 reads.
        if (st2) asm volatile("s_waitcnt vmcnt(6)" ::: "memory");
        else     asm volatile("s_waitcnt vmcnt(0)" ::: "memory");
        __builtin_amdgcn_s_barrier();
    }

    // ----- epilogue: C/D layout col = lane&15, row = (lane>>4)*4 + j -----
#pragma unroll
    for (int n = 0; n < 4; ++n) {
        const long cg = bcol + wc * 64 + n * 16 + fr;
        const float bv = bias[cg];
#pragma unroll
        for (int m = 0; m < 8; ++m) {
            const long rbase = brow + wr * 128 + m * 16 + fq * 4;
#pragma unroll
            for (int j = 0; j < 4; ++j)
                C[(rbase + j) * (long)N_DIM + cg] = acc[m][n][j] + bv;
        }
    }
}

// ---------- naive fallback ----------

__global__ __launch_bounds__(256) void naive_kernel(
    const float* __restrict__ x, const float* __restrict__ w,
    const float* __restrict__ bias, float* __restrict__ out, long total) {
    long gid = (long)blockIdx.x * blockDim.x + threadIdx.x;
    if (gid >= total) return;
    long m = gid / N_DIM, n = gid % N_DIM;
    const float* xr = x + m * (long)K_DIM;
    const float* wr = w + n * (long)K_DIM;
    float s = 0.f;
    for (int k = 0; k < K_DIM; ++k) {
        float wv = wr[k];
        float sg = (wv > 0.f) ? 1.f : ((wv < 0.f) ? -1.f : 0.f);
        s += xr[k] * sg;
    }
    out[gid] = s + bias[n];
}

// ---------- launch ----------

extern "C" void kernel_launch(void* const* d_in, const int* in_sizes, int n_in,
                              void* d_out, int out_size, void* d_ws, size_t ws_size,
                              hipStream_t stream) {
    const float* x    = (const float*)d_in[0];
    const float* w    = (const float*)d_in[1];
    const float* bias = (const float*)d_in[2];
    float* out = (float*)d_out;

    const size_t nA = (size_t)M_DIM * K_DIM;
    const size_t nB = (size_t)N_DIM * K_DIM;
    const size_t need_bytes = (nA + nB) * sizeof(unsigned short);

    if (ws_size >= need_bytes) {
        unsigned short* xb = (unsigned short*)d_ws;
        unsigned short* wb = xb + nA;
        {
            long nvec8 = (long)(nA / 8);
            cvt_x_kernel<<<(int)((nvec8 + 255) / 256), 256, 0, stream>>>(x, xb, nvec8);
        }
        {
            long nvec8 = (long)(nB / 8);
            cvt_w_kernel<<<(int)((nvec8 + 255) / 256), 256, 0, stream>>>(w, wb, nvec8);
        }
        dim3 grid((M_DIM / BM) * (N_DIM / BN));  // 32 * 16 = 512
        gemm256<<<grid, 512, 0, stream>>>(xb, wb, bias, out);
    } else {
        long total = (long)M_DIM * N_DIM;
        naive_kernel<<<(int)((total + 255) / 256), 256, 0, stream>>>(x, w, bias, out, total);
    }
}